// Round 9
// baseline (261.922 us; speedup 1.0000x reference)
//
#include <hip/hip_runtime.h>
#include <hip/hip_bf16.h>

// R8 post-mortem: occupancy 39->56% did NOT move time; stalls are correlated
// (per-phase MFMA ~116cyc vs ~600cyc weight latency -> 19% duty = MfmaUtil).
// Non-fused ~110us is fixed harness overhead (invariant R2-R8). R9: merge both
// Q-nets into one block, 32-row tiles: per-phase MFMA/wave 24->64-72 (2.7x),
// X staged once (obs traffic halves), A-frag ds_reads shared; LDS 69,632B
// keeps 2 blocks/CU = 16 waves/CU. launch_bounds(512,4) = 128 VGPR headroom.

#define NB 65536
#define MROWS 32
#define XSTR 296   // 592B row: %16==0; 16B-unit stride 37 (odd) -> max 2-way (free)
#define HSTR 264   // 528B row: %16==0; 16B-unit stride 33 (odd) -> max 2-way (free)

typedef __attribute__((ext_vector_type(8))) short short8;
typedef __attribute__((ext_vector_type(4))) short short4v;
typedef __attribute__((ext_vector_type(4))) float f32x4;

__device__ __forceinline__ float bf2f(unsigned short u){
  union { unsigned int i; float f; } x; x.i = ((unsigned int)u) << 16; return x.f;
}
__device__ __forceinline__ unsigned short f2bf(float f){
  unsigned int x = __float_as_uint(f);
  x += 0x7fffu + ((x >> 16) & 1u);   // RNE
  return (unsigned short)(x >> 16);
}
__device__ __forceinline__ float ldval(const void* p, int idx, int isbf16){
  return isbf16 ? bf2f(((const unsigned short*)p)[idx]) : ((const float*)p)[idx];
}

// wave-0 dtype sniff: low short of dword groups. bf16 -> N(0,1) exponents;
// fp32 -> random mantissa bits (~9% in range). Returns via LDS flag.
__device__ __forceinline__ int block_sniff(const void* obs, int tid, int* sflag){
  if (tid < 64) {
    unsigned short u = ((const unsigned short*)obs)[tid * 2];
    int e = (u >> 7) & 0xFF;
    unsigned long long m = __ballot(e >= 110 && e <= 132);
    if (tid == 0) *sflag = (__popcll(m) >= 32) ? 1 : 0;
  }
  __syncthreads();
  return *sflag;
}

struct KParams {
  const void* obs;
  const void* act;
  const unsigned short* w1t[2];   // swizzled [task][g16][kb9][l16][quad][8]
  const unsigned short* w2t[2];   // swizzled [task][g16][kb8][l16][quad][8]
  const unsigned short* w3t[2];
  const void* b1[2];
  const void* b2[2];
  const void* b3[2];
  const void* w4[2];
  const void* b4[2];
  const int* counts;
  const int* perm;
  void* out;
};

// ---- routing task: exact input precision ----
__device__ __forceinline__ int task_of(const void* obs, int b, int isbf16){
  float v0, v1, v2;
  if (isbf16) {
    short4v u = *(const short4v*)((const unsigned short*)obs + b * 256 + 252);
    v0 = bf2f((unsigned short)u[1]); v1 = bf2f((unsigned short)u[2]); v2 = bf2f((unsigned short)u[3]);
  } else {
    f32x4 u = *(const f32x4*)((const float*)obs + b * 256 + 252);
    v0 = u[1]; v1 = u[2]; v2 = u[3];
  }
  int t = 0; float m = v0;
  if (v1 > m) { m = v1; t = 1; }   // strict > => first-occurrence argmax (jnp)
  if (v2 > m) { t = 2; }
  return t;
}

// ---- K1: blocks 0..599 = weight prep (swizzled B-frag layout); blocks
// 600..855 = per-block task histogram (plain stores overwrite ws poison) ----
__global__ void prep_count(const void* q1W1, const void* q1W2, const void* q1W3,
                           const void* q2W1, const void* q2W2, const void* q2W3,
                           const void* obs, unsigned short* out,
                           int* hist, unsigned char* tasks){
  __shared__ int sflag;
  int tid = threadIdx.x;
  int isbf16 = block_sniff(obs, tid, &sflag);
  if (blockIdx.x >= 600) {             // ---- count role ----
    __shared__ int h[3];
    if (tid < 3) h[tid] = 0;
    __syncthreads();
    int blk = blockIdx.x - 600;
    int b = blk * 256 + tid;
    int t = task_of(obs, b, isbf16);
    tasks[b] = (unsigned char)t;
    atomicAdd(&h[t], 1);
    __syncthreads();
    if (tid < 3) hist[blk * 3 + tid] = h[tid];
    return;
  }
  // ---- prep role: thread writes 8 consecutive swizzled shorts ----
  int gid8 = (blockIdx.x * 256 + tid) * 8;
  int net = gid8 / 614400;
  int idx = gid8 - net * 614400;
  const void* W1 = net ? q2W1 : q1W1;
  const void* W2 = net ? q2W2 : q1W2;
  const void* W3 = net ? q2W3 : q1W3;
  short8 sv;
  if (idx < 221184) {                  // W1t: KC=9, per task 16*9*512=73728
    int t = idx / 73728; int i = idx - t * 73728;
    int g = i / 4608;  int r = i - g * 4608;
    int kb = r >> 9;   int q2 = r & 511;
    int l16 = q2 >> 5; int rem = q2 & 31;
    int n = g * 16 + l16;
    int k = kb * 32 + (rem & ~7);
    #pragma unroll
    for (int j = 0; j < 8; j++) {
      int kk = k + j;
      sv[j] = (kk < 264) ? (short)f2bf(ldval(W1, (t * 264 + kk) * 256 + n, isbf16)) : (short)0;
    }
  } else if (idx < 417792) {           // W2t: KC=8, per task 16*8*512=65536
    int j0 = idx - 221184;
    int t = j0 >> 16; int i = j0 & 65535;
    int g = i >> 12;  int r = i & 4095;
    int kb = r >> 9;  int q2 = r & 511;
    int l16 = q2 >> 5; int rem = q2 & 31;
    int n = g * 16 + l16;
    int k = kb * 32 + (rem & ~7);
    #pragma unroll
    for (int j = 0; j < 8; j++)
      sv[j] = (short)f2bf(ldval(W2, t * 65536 + (k + j) * 256 + n, isbf16));
  } else {                             // W3t
    int j0 = idx - 417792;
    int t = j0 >> 16; int i = j0 & 65535;
    int g = i >> 12;  int r = i & 4095;
    int kb = r >> 9;  int q2 = r & 511;
    int l16 = q2 >> 5; int rem = q2 & 31;
    int n = g * 16 + l16;
    int k = kb * 32 + (rem & ~7);
    #pragma unroll
    for (int j = 0; j < 8; j++)
      sv[j] = (short)f2bf(ldval(W3, t * 65536 + (k + j) * 256 + n, isbf16));
  }
  *(short8*)(out + net * 614400 + idx) = sv;
}

// ---- K2: scatter, atomic-free cross-block prefix from hists ----
__global__ void route_scatter(const unsigned char* __restrict__ tasks,
                              const int* __restrict__ hist,
                              int* counts, int* perm){
  __shared__ int sh[3][256];
  __shared__ int totals[3], pres[3], base[3], zz[3];
  int tid = threadIdx.x;
  int blk = blockIdx.x;
  sh[0][tid] = hist[tid * 3 + 0];
  sh[1][tid] = hist[tid * 3 + 1];
  sh[2][tid] = hist[tid * 3 + 2];
  if (tid < 3) zz[tid] = 0;
  __syncthreads();
  if (tid < 3) {
    int tot = 0, pre = 0;
    for (int b = 0; b < 256; b++) {
      int v = sh[tid][b];
      if (b < blk) pre += v;
      tot += v;
    }
    totals[tid] = tot; pres[tid] = pre;
  }
  __syncthreads();
  if (tid < 3) {
    int a0 = ((totals[0] + MROWS - 1) / MROWS) * MROWS;
    int a1 = ((totals[1] + MROWS - 1) / MROWS) * MROWS;
    int off = (tid == 0) ? 0 : (tid == 1) ? a0 : a0 + a1;
    base[tid] = off + pres[tid];
    if (blk == 0) counts[tid] = totals[tid];
  }
  __syncthreads();
  int b = blk * 256 + tid;
  int t = tasks[b];
  int r = atomicAdd(&zz[t], 1);
  perm[base[t] + r] = b;
}

// ---- one layer, one wave slice: 32 rows (mt=2) x 64 cols (nt=4) ----
template<int KC>
__device__ __forceinline__ void run_layer(const unsigned short* __restrict__ lin, int lstride,
                                          const unsigned short* __restrict__ wt,
                                          const void* bias, unsigned short* lout,
                                          int isbf16, int quad, int l16, int nbase){
  const unsigned short* wg = wt + (nbase >> 4) * (KC * 512) + l16 * 32 + quad * 8;
  f32x4 acc[2][4] = {};
  #pragma unroll
  for (int kb = 0; kb < KC; ++kb) {
    short8 bfr[4], afr[2];
    #pragma unroll
    for (int nt = 0; nt < 4; nt++)
      bfr[nt] = *(const short8*)(wg + nt * (KC * 512) + kb * 512);
    int ko = kb * 32 + quad * 8;
    #pragma unroll
    for (int mt = 0; mt < 2; mt++)
      afr[mt] = *(const short8*)(lin + (mt * 16 + l16) * lstride + ko);
    #pragma unroll
    for (int mt = 0; mt < 2; mt++)
      #pragma unroll
      for (int nt = 0; nt < 4; nt++)
        acc[mt][nt] = __builtin_amdgcn_mfma_f32_16x16x32_bf16(afr[mt], bfr[nt], acc[mt][nt], 0, 0, 0);
  }
  float bv[4];
  #pragma unroll
  for (int nt = 0; nt < 4; nt++) bv[nt] = ldval(bias, nbase + nt * 16 + l16, isbf16);
  #pragma unroll
  for (int mt = 0; mt < 2; mt++)
    #pragma unroll
    for (int nt = 0; nt < 4; nt++) {
      f32x4 a = acc[mt][nt];
      #pragma unroll
      for (int r = 0; r < 4; r++) {
        float v = fmaxf(a[r] + bv[nt], 0.f);   // C/D: col=lane&15, row=quad*4+r
        lout[(mt * 16 + quad * 4 + r) * HSTR + nbase + nt * 16 + l16] = f2bf(v);
      }
    }
  __syncthreads();
}

// ---- fused: 32-row task-uniform tile, BOTH nets per block. 512 thr / 8
// waves: wave w -> net=w>>2, cols (w&3)*64. LDS 69,632B -> 2 blocks/CU. ----
__global__ __launch_bounds__(512, 4) void fused_kernel(KParams p){
  __shared__ unsigned short X[MROWS * XSTR];        // 18,944 B; HB for net0 after L1
  __shared__ unsigned short H1[2][MROWS * HSTR];    // 2 x 16,896 B
  __shared__ unsigned short H2b[MROWS * HSTR];      // 16,896 B; HB for net1
  int* sflag = (int*)H1;                            // H1 unused until L1 epilogue

  int tid = threadIdx.x;
  int p0  = blockIdx.x * MROWS;
  int isbf16 = block_sniff(p.obs, tid, sflag);
  int c0 = p.counts[0], c1 = p.counts[1], c2 = p.counts[2];
  int off1 = ((c0 + MROWS - 1) / MROWS) * MROWS;
  int off2 = off1 + ((c1 + MROWS - 1) / MROWS) * MROWS;
  int task  = (p0 >= off2) ? 2 : ((p0 >= off1) ? 1 : 0);
  int segend = (task == 0) ? c0 : (task == 1) ? off1 + c1 : off2 + c2;

  // stage X once for both nets: 16 threads/row, chunks c = seg + 16j (0..35)
  {
    int srow = tid >> 4, seg = tid & 15;
    int pos = p0 + srow;
    int r = (pos < segend) ? p.perm[pos] : -1;
    #pragma unroll
    for (int j = 0; j < 3; ++j) {
      int c = seg + 16 * j;
      if (c <= 35) {
        short8 sv = {0,0,0,0,0,0,0,0};
        if (r >= 0 && c < 33) {
          if (isbf16) {
            const unsigned short* src = (c < 32) ? ((const unsigned short*)p.obs + r * 256 + c * 8)
                                                 : ((const unsigned short*)p.act + r * 8);
            sv = *(const short8*)src;
          } else {
            const float* src = (c < 32) ? ((const float*)p.obs + r * 256 + c * 8)
                                        : ((const float*)p.act + r * 8);
            f32x4 a = *(const f32x4*)src;
            f32x4 b = *(const f32x4*)(src + 4);
            #pragma unroll
            for (int q = 0; q < 4; q++) { sv[q] = (short)f2bf(a[q]); sv[4 + q] = (short)f2bf(b[q]); }
          }
        }
        *(short8*)(X + srow * XSTR + c * 8) = sv;
      }
    }
  }
  __syncthreads();

  int wave = tid >> 6, lane = tid & 63, quad = lane >> 4, l16 = lane & 15;
  int net  = wave >> 2;
  int nbase = (wave & 3) * 64;          // 64 cols per wave per net

  unsigned short* HB = net ? H2b : X;   // X dead after L1 (both nets consumed it)
  int bsz = isbf16 ? 2 : 4;
  run_layer<9>(X,       XSTR, p.w1t[net] + task * 73728, (const char*)p.b1[net] + task * 256 * bsz, H1[net], isbf16, quad, l16, nbase);
  run_layer<8>(H1[net], HSTR, p.w2t[net] + task * 65536, (const char*)p.b2[net] + task * 256 * bsz, HB,      isbf16, quad, l16, nbase);
  run_layer<8>(HB,      HSTR, p.w3t[net] + task * 65536, (const char*)p.b3[net] + task * 256 * bsz, H1[net], isbf16, quad, l16, nbase);

  // layer 4: y = h3 . w4 + b4. tid -> net=tid>>8, row=(tid>>3)&31, seg=tid&7
  {
    int onet = tid >> 8, row = (tid >> 3) & 31, seg = tid & 7;
    const unsigned short* h3 = H1[onet];
    float s = 0.f;
    #pragma unroll
    for (int kk = 0; kk < 32; kk += 8) {
      short8 hv = *(const short8*)(h3 + row * HSTR + seg * 32 + kk);
      float wv[8];
      if (isbf16) {
        const unsigned short* w4p = (const unsigned short*)p.w4[onet] + task * 256 + seg * 32 + kk;
        short8 t = *(const short8*)w4p;
        #pragma unroll
        for (int j = 0; j < 8; j++) wv[j] = bf2f((unsigned short)t[j]);
      } else {
        const float* w4p = (const float*)p.w4[onet] + task * 256 + seg * 32 + kk;
        f32x4 a = *(const f32x4*)w4p;
        f32x4 b = *(const f32x4*)(w4p + 4);
        #pragma unroll
        for (int j = 0; j < 4; j++) { wv[j] = a[j]; wv[4 + j] = b[j]; }
      }
      #pragma unroll
      for (int j = 0; j < 8; j++)
        s += bf2f((unsigned short)hv[j]) * wv[j];
    }
    s += __shfl_xor(s, 1);
    s += __shfl_xor(s, 2);
    s += __shfl_xor(s, 4);
    if (seg == 0) {
      int pos = p0 + row;
      if (pos < segend) {
        int r = p.perm[pos];
        float y = s + ldval(p.b4[onet], task, isbf16);
        if (isbf16) ((unsigned short*)p.out)[onet * NB + r] = f2bf(y);
        else        ((float*)p.out)[onet * NB + r] = y;
      }
    }
  }
}

extern "C" void kernel_launch(void* const* d_in, const int* in_sizes, int n_in,
                              void* d_out, int out_size, void* d_ws, size_t ws_size,
                              hipStream_t stream) {
  char* ws = (char*)d_ws;
  int* counts  = (int*)ws;                                // 3 ints @0 (K2 stores)
  int* hist    = (int*)(ws + 64);                         // 256*3 ints (K1 stores)
  unsigned char* tasks = (unsigned char*)(ws + 3200);     // 65536 B (K1 stores)
  int* perm    = (int*)(ws + 68800);                      // <=65600 ints (K2 stores)
  unsigned short* wts  = (unsigned short*)(ws + 331520);  // 2*614400 bf16 (K1 stores)

  const void* obs = d_in[0];
  const void* act = d_in[1];

  prep_count<<<856, 256, 0, stream>>>(d_in[2], d_in[4], d_in[6],
                                      d_in[10], d_in[12], d_in[14],
                                      obs, wts, hist, tasks);
  route_scatter<<<256, 256, 0, stream>>>(tasks, hist, counts, perm);

  KParams kp;
  kp.obs = obs; kp.act = act;
  for (int q = 0; q < 2; q++) {
    int base = 2 + q * 8;
    kp.b1[q] = d_in[base + 1];
    kp.b2[q] = d_in[base + 3];
    kp.b3[q] = d_in[base + 5];
    kp.w4[q] = d_in[base + 6];
    kp.b4[q] = d_in[base + 7];
    kp.w1t[q] = wts + q * 614400;
    kp.w2t[q] = wts + q * 614400 + 221184;
    kp.w3t[q] = wts + q * 614400 + 417792;
  }
  kp.counts = counts; kp.perm = perm;
  kp.out = d_out;

  // 2050 tiles of 32 rows covers worst-case per-task padding; both nets/block
  fused_kernel<<<2050, 512, 0, stream>>>(kp);
}

// Round 10
// 241.210 us; speedup vs baseline: 1.0859x; 1.0859x over previous
//
#include <hip/hip_runtime.h>
#include <hip/hip_bf16.h>

// R9 post-mortem (FAILED 113->152us): merging nets doubled weight traffic
// (1.68GB); R7/R8/R9 deliver 7.6/9.9/11.0 TB/s of weight reads -> path
// saturates ~11 TB/s. Model: obs stream (~17MB/XCD) thrashes 4MB L2 -> weight
// re-reads served by L3 (~11 TB/s ceiling). R10: back to R8 structure (48-row,
// 3 blk/CU, 24 w/CU) + NONTEMPORAL obs/act staging + nt out stores (keep
// weights L2-resident) + net-interleaved grid for temporal obs reuse.

#define NB 65536
#define MROWS 48   // row tile (mt=3 x 16)
#define XSTR 296   // 592B row: %16==0, 16B-unit stride 37 (odd) -> max 2-way (free)
#define HSTR 264   // 528B row: %16==0, 16B-unit stride 33 (odd) -> max 2-way (free)

typedef __attribute__((ext_vector_type(8))) short short8;
typedef __attribute__((ext_vector_type(4))) short short4v;
typedef __attribute__((ext_vector_type(4))) float f32x4;

__device__ __forceinline__ float bf2f(unsigned short u){
  union { unsigned int i; float f; } x; x.i = ((unsigned int)u) << 16; return x.f;
}
__device__ __forceinline__ unsigned short f2bf(float f){
  unsigned int x = __float_as_uint(f);
  x += 0x7fffu + ((x >> 16) & 1u);   // RNE
  return (unsigned short)(x >> 16);
}
__device__ __forceinline__ float ldval(const void* p, int idx, int isbf16){
  return isbf16 ? bf2f(((const unsigned short*)p)[idx]) : ((const float*)p)[idx];
}

// wave-0 dtype sniff: low short of dword groups. bf16 -> N(0,1) exponents;
// fp32 -> random mantissa bits (~9% in range). Returns via LDS flag.
__device__ __forceinline__ int block_sniff(const void* obs, int tid, int* sflag){
  if (tid < 64) {
    unsigned short u = ((const unsigned short*)obs)[tid * 2];
    int e = (u >> 7) & 0xFF;
    unsigned long long m = __ballot(e >= 110 && e <= 132);
    if (tid == 0) *sflag = (__popcll(m) >= 32) ? 1 : 0;
  }
  __syncthreads();
  return *sflag;
}

struct KParams {
  const void* obs;
  const void* act;
  const unsigned short* w1t[2];   // swizzled [task][g16][kb9][l16][quad][8]
  const unsigned short* w2t[2];   // swizzled [task][g16][kb8][l16][quad][8]
  const unsigned short* w3t[2];
  const void* b1[2];
  const void* b2[2];
  const void* b3[2];
  const void* w4[2];
  const void* b4[2];
  const int* counts;
  const int* perm;
  void* out;
};

// ---- routing task: exact input precision ----
__device__ __forceinline__ int task_of(const void* obs, int b, int isbf16){
  float v0, v1, v2;
  if (isbf16) {
    short4v u = *(const short4v*)((const unsigned short*)obs + b * 256 + 252);
    v0 = bf2f((unsigned short)u[1]); v1 = bf2f((unsigned short)u[2]); v2 = bf2f((unsigned short)u[3]);
  } else {
    f32x4 u = *(const f32x4*)((const float*)obs + b * 256 + 252);
    v0 = u[1]; v1 = u[2]; v2 = u[3];
  }
  int t = 0; float m = v0;
  if (v1 > m) { m = v1; t = 1; }   // strict > => first-occurrence argmax (jnp)
  if (v2 > m) { t = 2; }
  return t;
}

// ---- K1: blocks 0..599 = weight prep (swizzled B-frag layout); blocks
// 600..855 = per-block task histogram (plain stores overwrite ws poison) ----
__global__ void prep_count(const void* q1W1, const void* q1W2, const void* q1W3,
                           const void* q2W1, const void* q2W2, const void* q2W3,
                           const void* obs, unsigned short* out,
                           int* hist, unsigned char* tasks){
  __shared__ int sflag;
  int tid = threadIdx.x;
  int isbf16 = block_sniff(obs, tid, &sflag);
  if (blockIdx.x >= 600) {             // ---- count role ----
    __shared__ int h[3];
    if (tid < 3) h[tid] = 0;
    __syncthreads();
    int blk = blockIdx.x - 600;
    int b = blk * 256 + tid;
    int t = task_of(obs, b, isbf16);
    tasks[b] = (unsigned char)t;
    atomicAdd(&h[t], 1);
    __syncthreads();
    if (tid < 3) hist[blk * 3 + tid] = h[tid];
    return;
  }
  // ---- prep role: thread writes 8 consecutive swizzled shorts ----
  int gid8 = (blockIdx.x * 256 + tid) * 8;
  int net = gid8 / 614400;
  int idx = gid8 - net * 614400;
  const void* W1 = net ? q2W1 : q1W1;
  const void* W2 = net ? q2W2 : q1W2;
  const void* W3 = net ? q2W3 : q1W3;
  short8 sv;
  if (idx < 221184) {                  // W1t: KC=9, per task 16*9*512=73728
    int t = idx / 73728; int i = idx - t * 73728;
    int g = i / 4608;  int r = i - g * 4608;
    int kb = r >> 9;   int q2 = r & 511;
    int l16 = q2 >> 5; int rem = q2 & 31;
    int n = g * 16 + l16;
    int k = kb * 32 + (rem & ~7);
    #pragma unroll
    for (int j = 0; j < 8; j++) {
      int kk = k + j;
      sv[j] = (kk < 264) ? (short)f2bf(ldval(W1, (t * 264 + kk) * 256 + n, isbf16)) : (short)0;
    }
  } else if (idx < 417792) {           // W2t: KC=8, per task 16*8*512=65536
    int j0 = idx - 221184;
    int t = j0 >> 16; int i = j0 & 65535;
    int g = i >> 12;  int r = i & 4095;
    int kb = r >> 9;  int q2 = r & 511;
    int l16 = q2 >> 5; int rem = q2 & 31;
    int n = g * 16 + l16;
    int k = kb * 32 + (rem & ~7);
    #pragma unroll
    for (int j = 0; j < 8; j++)
      sv[j] = (short)f2bf(ldval(W2, t * 65536 + (k + j) * 256 + n, isbf16));
  } else {                             // W3t
    int j0 = idx - 417792;
    int t = j0 >> 16; int i = j0 & 65535;
    int g = i >> 12;  int r = i & 4095;
    int kb = r >> 9;  int q2 = r & 511;
    int l16 = q2 >> 5; int rem = q2 & 31;
    int n = g * 16 + l16;
    int k = kb * 32 + (rem & ~7);
    #pragma unroll
    for (int j = 0; j < 8; j++)
      sv[j] = (short)f2bf(ldval(W3, t * 65536 + (k + j) * 256 + n, isbf16));
  }
  *(short8*)(out + net * 614400 + idx) = sv;
}

// ---- K2: scatter, atomic-free cross-block prefix from hists ----
__global__ void route_scatter(const unsigned char* __restrict__ tasks,
                              const int* __restrict__ hist,
                              int* counts, int* perm){
  __shared__ int sh[3][256];
  __shared__ int totals[3], pres[3], base[3], zz[3];
  int tid = threadIdx.x;
  int blk = blockIdx.x;
  sh[0][tid] = hist[tid * 3 + 0];
  sh[1][tid] = hist[tid * 3 + 1];
  sh[2][tid] = hist[tid * 3 + 2];
  if (tid < 3) zz[tid] = 0;
  __syncthreads();
  if (tid < 3) {
    int tot = 0, pre = 0;
    for (int b = 0; b < 256; b++) {
      int v = sh[tid][b];
      if (b < blk) pre += v;
      tot += v;
    }
    totals[tid] = tot; pres[tid] = pre;
  }
  __syncthreads();
  if (tid < 3) {
    int a0 = ((totals[0] + MROWS - 1) / MROWS) * MROWS;
    int a1 = ((totals[1] + MROWS - 1) / MROWS) * MROWS;
    int off = (tid == 0) ? 0 : (tid == 1) ? a0 : a0 + a1;
    base[tid] = off + pres[tid];
    if (blk == 0) counts[tid] = totals[tid];
  }
  __syncthreads();
  int b = blk * 256 + tid;
  int t = tasks[b];
  int r = atomicAdd(&zz[t], 1);
  perm[base[t] + r] = b;
}

// ---- one layer: template-unrolled K, per-wave 48 rows x 32 cols ----
template<int KC>
__device__ __forceinline__ void run_layer(const unsigned short* __restrict__ lin, int lstride,
                                          const unsigned short* __restrict__ wt,
                                          const void* bias, unsigned short* lout,
                                          int isbf16, int wave, int quad, int l16, int nbase){
  const unsigned short* wg = wt + (wave * 2) * (KC * 512) + l16 * 32 + quad * 8;
  short8 bfr[KC][2];
  #pragma unroll
  for (int kb = 0; kb < KC; ++kb) {
    bfr[kb][0] = *(const short8*)(wg + kb * 512);
    bfr[kb][1] = *(const short8*)(wg + KC * 512 + kb * 512);
  }
  f32x4 acc[3][2] = {};
  #pragma unroll
  for (int kb = 0; kb < KC; ++kb) {
    short8 afr[3];
    int ko = kb * 32 + quad * 8;
    #pragma unroll
    for (int mt = 0; mt < 3; mt++)
      afr[mt] = *(const short8*)(lin + (mt * 16 + l16) * lstride + ko);
    #pragma unroll
    for (int mt = 0; mt < 3; mt++)
      #pragma unroll
      for (int nt = 0; nt < 2; nt++)
        acc[mt][nt] = __builtin_amdgcn_mfma_f32_16x16x32_bf16(afr[mt], bfr[kb][nt], acc[mt][nt], 0, 0, 0);
  }
  float bv[2];
  #pragma unroll
  for (int nt = 0; nt < 2; nt++) bv[nt] = ldval(bias, nbase + nt * 16 + l16, isbf16);
  #pragma unroll
  for (int mt = 0; mt < 3; mt++)
    #pragma unroll
    for (int nt = 0; nt < 2; nt++) {
      f32x4 a = acc[mt][nt];
      #pragma unroll
      for (int r = 0; r < 4; r++) {
        float v = fmaxf(a[r] + bv[nt], 0.f);   // C/D: col=lane&15, row=quad*4+r
        lout[(mt * 16 + quad * 4 + r) * HSTR + nbase + nt * 16 + l16] = f2bf(v);
      }
    }
  __syncthreads();
}

// ---- fused: 48-row task-uniform tile, 512 thr / 8 waves; LDS 53,760B ->
// 3 blocks/CU = 24 waves/CU; wave = 48 rows x 32 cols. Net interleaved in
// blockIdx.x (tile*2+net) so both nets' reads of one obs row are adjacent. ----
__global__ __launch_bounds__(512, 6) void fused_kernel(KParams p){
  __shared__ unsigned short X[MROWS * XSTR];   // 28,416 B ; reused as HB after L1
  __shared__ unsigned short HA[MROWS * HSTR];  // 25,344 B  (total 53,760)
  unsigned short* HB = X;
  int* sflag = (int*)HA;                       // aliased: HA unused until L1 epi

  int tid = threadIdx.x;
  int net  = blockIdx.x & 1;
  int tile = blockIdx.x >> 1;
  int p0  = tile * MROWS;
  int isbf16 = block_sniff(p.obs, tid, sflag);
  int c0 = p.counts[0], c1 = p.counts[1], c2 = p.counts[2];
  int off1 = ((c0 + MROWS - 1) / MROWS) * MROWS;
  int off2 = off1 + ((c1 + MROWS - 1) / MROWS) * MROWS;
  int task  = (p0 >= off2) ? 2 : ((p0 >= off1) ? 1 : 0);
  int segend = (task == 0) ? c0 : (task == 1) ? off1 + c1 : off2 + c2;

  // stage X: 8 threads/row (tids 0..383); NONTEMPORAL loads (don't evict
  // weights from L2); validity is arithmetic
  if (tid < MROWS * 8) {
    int srow = tid >> 3, seg = tid & 7;
    int pos = p0 + srow;
    int r = (pos < segend) ? p.perm[pos] : -1;
    #pragma unroll
    for (int j = 0; j < 5; ++j) {
      int c = seg + 8 * j;
      if (c <= 35) {
        short8 sv = {0,0,0,0,0,0,0,0};
        if (r >= 0 && c < 33) {
          if (isbf16) {
            const unsigned short* src = (c < 32) ? ((const unsigned short*)p.obs + r * 256 + c * 8)
                                                 : ((const unsigned short*)p.act + r * 8);
            sv = __builtin_nontemporal_load((const short8*)src);
          } else {
            const float* src = (c < 32) ? ((const float*)p.obs + r * 256 + c * 8)
                                        : ((const float*)p.act + r * 8);
            f32x4 a = __builtin_nontemporal_load((const f32x4*)src);
            f32x4 b = __builtin_nontemporal_load((const f32x4*)(src + 4));
            #pragma unroll
            for (int q = 0; q < 4; q++) { sv[q] = (short)f2bf(a[q]); sv[4 + q] = (short)f2bf(b[q]); }
          }
        }
        *(short8*)(X + srow * XSTR + c * 8) = sv;
      }
    }
  }
  __syncthreads();

  int wave = tid >> 6, lane = tid & 63, quad = lane >> 4, l16 = lane & 15;
  int nbase = wave * 32;   // each of 8 waves owns 32 output cols

  int bsz = isbf16 ? 2 : 4;
  run_layer<9>(X,  XSTR, p.w1t[net] + task * 73728, (const char*)p.b1[net] + task * 256 * bsz, HA, isbf16, wave, quad, l16, nbase);
  run_layer<8>(HA, HSTR, p.w2t[net] + task * 65536, (const char*)p.b2[net] + task * 256 * bsz, HB, isbf16, wave, quad, l16, nbase);
  run_layer<8>(HB, HSTR, p.w3t[net] + task * 65536, (const char*)p.b3[net] + task * 256 * bsz, HA, isbf16, wave, quad, l16, nbase);

  // layer 4: y = h3 . w4 + b4  (8 threads/row, 3-level shuffle)
  if (tid < MROWS * 8) {
    int row = tid >> 3, seg = tid & 7;
    float s = 0.f;
    #pragma unroll
    for (int kk = 0; kk < 32; kk += 8) {
      short8 hv = *(const short8*)(HA + row * HSTR + seg * 32 + kk);
      float wv[8];
      if (isbf16) {
        const unsigned short* w4p = (const unsigned short*)p.w4[net] + task * 256 + seg * 32 + kk;
        short8 t = *(const short8*)w4p;
        #pragma unroll
        for (int j = 0; j < 8; j++) wv[j] = bf2f((unsigned short)t[j]);
      } else {
        const float* w4p = (const float*)p.w4[net] + task * 256 + seg * 32 + kk;
        f32x4 a = *(const f32x4*)w4p;
        f32x4 b = *(const f32x4*)(w4p + 4);
        #pragma unroll
        for (int j = 0; j < 4; j++) { wv[j] = a[j]; wv[4 + j] = b[j]; }
      }
      #pragma unroll
      for (int j = 0; j < 8; j++)
        s += bf2f((unsigned short)hv[j]) * wv[j];
    }
    s += __shfl_xor(s, 1);
    s += __shfl_xor(s, 2);
    s += __shfl_xor(s, 4);
    if (seg == 0) {
      int pos = p0 + row;
      if (pos < segend) {
        int r = p.perm[pos];
        float y = s + ldval(p.b4[net], task, isbf16);
        if (isbf16) __builtin_nontemporal_store(f2bf(y), (unsigned short*)p.out + net * NB + r);
        else        __builtin_nontemporal_store(y, (float*)p.out + net * NB + r);
      }
    }
  }
}

extern "C" void kernel_launch(void* const* d_in, const int* in_sizes, int n_in,
                              void* d_out, int out_size, void* d_ws, size_t ws_size,
                              hipStream_t stream) {
  char* ws = (char*)d_ws;
  int* counts  = (int*)ws;                                // 3 ints @0 (K2 stores)
  int* hist    = (int*)(ws + 64);                         // 256*3 ints (K1 stores)
  unsigned char* tasks = (unsigned char*)(ws + 3200);     // 65536 B (K1 stores)
  int* perm    = (int*)(ws + 68800);                      // <=65632 ints (K2 stores)
  unsigned short* wts  = (unsigned short*)(ws + 331520);  // 2*614400 bf16 (K1 stores)

  const void* obs = d_in[0];
  const void* act = d_in[1];

  prep_count<<<856, 256, 0, stream>>>(d_in[2], d_in[4], d_in[6],
                                      d_in[10], d_in[12], d_in[14],
                                      obs, wts, hist, tasks);
  route_scatter<<<256, 256, 0, stream>>>(tasks, hist, counts, perm);

  KParams kp;
  kp.obs = obs; kp.act = act;
  for (int q = 0; q < 2; q++) {
    int base = 2 + q * 8;
    kp.b1[q] = d_in[base + 1];
    kp.b2[q] = d_in[base + 3];
    kp.b3[q] = d_in[base + 5];
    kp.w4[q] = d_in[base + 6];
    kp.b4[q] = d_in[base + 7];
    kp.w1t[q] = wts + q * 614400;
    kp.w2t[q] = wts + q * 614400 + 221184;
    kp.w3t[q] = wts + q * 614400 + 417792;
  }
  kp.counts = counts; kp.perm = perm;
  kp.out = d_out;

  // 1368 tiles of 48 rows x 2 nets, net interleaved fast
  fused_kernel<<<2736, 512, 0, stream>>>(kp);
}